// Round 3
// baseline (422.963 us; speedup 1.0000x reference)
//
#include <hip/hip_runtime.h>
#include <math.h>

// B=16, H=12, S=1024, D=64.  BH=192, rows = B*H*S = 196608.
// R3: SINGLE KERNEL.  No prep pass, no workspace traffic at all.
// Per (bh,qb) block:
//   prologue: stage my 256 x-rows fp32->bf16 in LDS, project Q (Wq fragments
//             built inline from fp32 global), Q held in registers.
//   main loop (16 x 64-key blocks, 2 barriers each):
//     proj phase: each lane loads its x-fragment straight from fp32 global
//                 (wave covers 16 full rows, coalesced; L2/L3-hot), converts,
//                 projects K and kappa-permuted Vt into LDS via MFMA.
//     compute phase: QK -> exp2 -> PV, P^T fed to MFMA straight from regs.
//   epilogue: fused @ Wo (kappa-folded fp32 loads) + bo.
// LDS = union(prologue 36.9KB, W/K/V 36.9KB) -> 4 blocks/CU @ VGPR<=128.
//
// KEY-PERMUTATION TRICK (unchanged): P^T exits QK in C-layout; reinterpreted
// as a B-fragment it supplies key kappa(s) at MFMA k-slot s.  Vt and Wo are
// stored/loaded pre-permuted by kappa so P and O feed MFMA from registers.
// kappa: s = 16t + 4q + r  ->  32*(t>>1) + 8*q + 4*(t&1) + r.

typedef __bf16 bf16x8 __attribute__((ext_vector_type(8)));
typedef float  f32x4  __attribute__((ext_vector_type(4)));

#define MFMA(a, b, c) __builtin_amdgcn_mfma_f32_16x16x32_bf16((a), (b), (c), 0, 0, 0)

static constexpr int S = 1024;
static constexpr int PAD = 72;      // 144 B row stride: 16B-aligned, breaks 128B aliasing
// Q prescale: 1/sqrt(64) * log2(e)  -> scores arrive pre-scaled for exp2
static constexpr float QSCALE = 0.125f * 1.4426950408889634f;

__device__ inline unsigned long long pack4bf(float a, float b, float c, float d) {
    union { __bf16 h[4]; unsigned long long u; } pk;
    pk.h[0] = (__bf16)a; pk.h[1] = (__bf16)b; pk.h[2] = (__bf16)c; pk.h[3] = (__bf16)d;
    return pk.u;
}

union frag_u { bf16x8 v; unsigned long long u[2]; };

// ---------------------------------------------------------------------------
__global__ __launch_bounds__(256, 4) void attn(
    const float* __restrict__ x,
    const float* __restrict__ Wq, const float* __restrict__ bq,
    const float* __restrict__ Wk, const float* __restrict__ bk,
    const float* __restrict__ Wv, const float* __restrict__ bv,
    const float* __restrict__ Wo, const float* __restrict__ bo,
    float* __restrict__ out)
{
    __shared__ __align__(16) union {
        __bf16 xq[256][PAD];            // prologue: x (q rows), then Q roundtrip
        struct {
            __bf16 w[2][64][PAD];       // Wk, Wv bf16 tiles (persist main loop)
            __bf16 k[64][PAD];          // K tile [key][d]
            __bf16 v[64][PAD];          // Vt tile [d][key-kappa]
        } m;
    } L;

    const int tid = threadIdx.x;
    const int w = tid >> 6, lane = tid & 63, m = lane & 15, quad = lane >> 4;
    const int bh = blockIdx.x;
    const int q0 = blockIdx.y * 256 + w * 64;

    // ---- prologue: stage my 256 x-rows fp32 -> bf16 ----
    const float* xq32 = x + ((size_t)bh * 1024 + blockIdx.y * 256) * 64;
    #pragma unroll
    for (int i = tid * 4; i < 16384; i += 1024) {
        float4 v = *(const float4*)(xq32 + i);
        int r = i >> 6, c = i & 63;
        *(unsigned long long*)&L.xq[r][c] = pack4bf(v.x, v.y, v.z, v.w);
    }
    __syncthreads();
    bf16x8 xqf[4][2];
    #pragma unroll
    for (int g = 0; g < 4; g++) {
        xqf[g][0] = *(const bf16x8*)&L.xq[w * 64 + g * 16 + m][quad * 8];
        xqf[g][1] = *(const bf16x8*)&L.xq[w * 64 + g * 16 + m][32 + quad * 8];
    }
    __syncthreads();

    // ---- project Q (Wq fragments built inline from fp32 global) ----
    #pragma unroll
    for (int et = 0; et < 4; et++) {
        const float* wqrow = Wq + (size_t)(et * 16 + m) * 64;
        float4 a0 = *(const float4*)(wqrow + quad * 8);
        float4 a1 = *(const float4*)(wqrow + quad * 8 + 4);
        float4 a2 = *(const float4*)(wqrow + 32 + quad * 8);
        float4 a3 = *(const float4*)(wqrow + 36 + quad * 8);
        frag_u wf0, wf1;
        wf0.u[0] = pack4bf(a0.x, a0.y, a0.z, a0.w);
        wf0.u[1] = pack4bf(a1.x, a1.y, a1.z, a1.w);
        wf1.u[0] = pack4bf(a2.x, a2.y, a2.z, a2.w);
        wf1.u[1] = pack4bf(a3.x, a3.y, a3.z, a3.w);
        float4 bias = *(const float4*)(bq + et * 16 + quad * 4);
        #pragma unroll
        for (int g = 0; g < 4; g++) {
            f32x4 acc = {0.f, 0.f, 0.f, 0.f};
            acc = MFMA(wf0.v, xqf[g][0], acc);
            acc = MFMA(wf1.v, xqf[g][1], acc);
            *(unsigned long long*)&L.xq[w * 64 + g * 16 + m][et * 16 + quad * 4] =
                pack4bf((acc[0] + bias.x) * QSCALE, (acc[1] + bias.y) * QSCALE,
                        (acc[2] + bias.z) * QSCALE, (acc[3] + bias.w) * QSCALE);
        }
    }
    __syncthreads();
    bf16x8 qf[4][2];
    #pragma unroll
    for (int g = 0; g < 4; g++) {
        qf[g][0] = *(const bf16x8*)&L.xq[w * 64 + g * 16 + m][quad * 8];
        qf[g][1] = *(const bf16x8*)&L.xq[w * 64 + g * 16 + m][32 + quad * 8];
    }
    __syncthreads();

    // ---- stage Wk/Wv bf16 tiles into LDS (aliases xq; qf already in regs) ----
    #pragma unroll
    for (int i = tid * 4; i < 4096; i += 1024) {
        int r = i >> 6, c = i & 63;
        float4 a = *(const float4*)(Wk + i);
        *(unsigned long long*)&L.m.w[0][r][c] = pack4bf(a.x, a.y, a.z, a.w);
        float4 b = *(const float4*)(Wv + i);
        *(unsigned long long*)&L.m.w[1][r][c] = pack4bf(b.x, b.y, b.z, b.w);
    }
    float4 bkr[4];
    float  bvr[4];
    #pragma unroll
    for (int et = 0; et < 4; et++) {
        bkr[et] = *(const float4*)(bk + et * 16 + quad * 4);
        bvr[et] = bv[et * 16 + m];
    }

    f32x4 o[4][4];
    float lsum[4] = {0.f, 0.f, 0.f, 0.f};
    #pragma unroll
    for (int g = 0; g < 4; g++)
        #pragma unroll
        for (int n = 0; n < 4; n++) o[g][n] = {0.f, 0.f, 0.f, 0.f};

    const float* xk32 = x + (size_t)bh * 1024 * 64;          // fp32 keys, this bh
    const int p0 = 32 * (w >> 1) + 8 * quad + 4 * (w & 1);   // kappa base, tile t=w

    for (int kb = 0; kb < 16; kb++) {
        __syncthreads();                     // A: prev compute done, w staged
        // ---- proj phase: x-fragment straight from global fp32, K/V -> LDS ----
        {
            const float* xrow = xk32 + (size_t)(kb * 64 + w * 16 + m) * 64;
            float4 a0 = *(const float4*)(xrow + quad * 8);
            float4 a1 = *(const float4*)(xrow + quad * 8 + 4);
            float4 a2 = *(const float4*)(xrow + 32 + quad * 8);
            float4 a3 = *(const float4*)(xrow + 36 + quad * 8);
            frag_u xk0, xk1;
            xk0.u[0] = pack4bf(a0.x, a0.y, a0.z, a0.w);
            xk0.u[1] = pack4bf(a1.x, a1.y, a1.z, a1.w);
            xk1.u[0] = pack4bf(a2.x, a2.y, a2.z, a2.w);
            xk1.u[1] = pack4bf(a3.x, a3.y, a3.z, a3.w);
            #pragma unroll
            for (int et = 0; et < 4; et++) {
                bf16x8 kw0 = *(const bf16x8*)&L.m.w[0][et * 16 + m][quad * 8];
                bf16x8 kw1 = *(const bf16x8*)&L.m.w[0][et * 16 + m][32 + quad * 8];
                f32x4 ka = {0.f, 0.f, 0.f, 0.f};
                ka = MFMA(kw0, xk0.v, ka);
                ka = MFMA(kw1, xk1.v, ka);
                *(unsigned long long*)&L.m.k[w * 16 + m][et * 16 + quad * 4] =
                    pack4bf(ka[0] + bkr[et].x, ka[1] + bkr[et].y,
                            ka[2] + bkr[et].z, ka[3] + bkr[et].w);
                bf16x8 vw0 = *(const bf16x8*)&L.m.w[1][et * 16 + m][quad * 8];
                bf16x8 vw1 = *(const bf16x8*)&L.m.w[1][et * 16 + m][32 + quad * 8];
                f32x4 va = {0.f, 0.f, 0.f, 0.f};
                va = MFMA(xk0.v, vw0, va);
                va = MFMA(xk1.v, vw1, va);
                *(unsigned long long*)&L.m.v[et * 16 + m][p0] =
                    pack4bf(va[0] + bvr[et], va[1] + bvr[et],
                            va[2] + bvr[et], va[3] + bvr[et]);
            }
        }
        __syncthreads();                     // B: K/V tile ready
        // ---- compute phase: QK -> exp2 -> PV (unchanged inner loop) ----
        #pragma unroll
        for (int gp = 0; gp < 2; gp++) {
            frag_u pb[2][2];
            #pragma unroll
            for (int t = 0; t < 4; t++) {
                bf16x8 ka0 = *(const bf16x8*)&L.m.k[t * 16 + m][quad * 8];
                bf16x8 ka1 = *(const bf16x8*)&L.m.k[t * 16 + m][32 + quad * 8];
                #pragma unroll
                for (int gl = 0; gl < 2; gl++) {
                    const int g = gp * 2 + gl;
                    f32x4 acc = {0.f, 0.f, 0.f, 0.f};
                    acc = MFMA(ka0, qf[g][0], acc);
                    acc = MFMA(ka1, qf[g][1], acc);
                    float e0 = __builtin_amdgcn_exp2f(acc[0]);
                    float e1 = __builtin_amdgcn_exp2f(acc[1]);
                    float e2 = __builtin_amdgcn_exp2f(acc[2]);
                    float e3 = __builtin_amdgcn_exp2f(acc[3]);
                    lsum[g] += (e0 + e1) + (e2 + e3);
                    pb[gl][t >> 1].u[t & 1] = pack4bf(e0, e1, e2, e3);
                }
            }
            #pragma unroll
            for (int n = 0; n < 4; n++) {
                bf16x8 va0 = *(const bf16x8*)&L.m.v[n * 16 + m][quad * 8];
                bf16x8 va1 = *(const bf16x8*)&L.m.v[n * 16 + m][32 + quad * 8];
                #pragma unroll
                for (int gl = 0; gl < 2; gl++) {
                    const int g = gp * 2 + gl;
                    o[g][n] = MFMA(va0, pb[gl][0].v, o[g][n]);
                    o[g][n] = MFMA(va1, pb[gl][1].v, o[g][n]);
                }
            }
        }
    }

    // ---- epilogue: l reduce, O^T regs -> A-fragments, fused @ Wo + bo ----
    #pragma unroll
    for (int g = 0; g < 4; g++) {
        lsum[g] += __shfl_xor(lsum[g], 16);
        lsum[g] += __shfl_xor(lsum[g], 32);
    }

    // Wo fragments with kappa folded into the load addresses:
    // wf[et][0] slots = Wo[e][4q..4q+3], Wo[e][16+4q..+3];
    // wf[et][1] slots = Wo[e][32+4q..+3], Wo[e][48+4q..+3].
    bf16x8 wf[4][2];
    #pragma unroll
    for (int et = 0; et < 4; et++) {
        const float* worow = Wo + (size_t)(et * 16 + m) * 64;
        float4 c0 = *(const float4*)(worow + 4 * quad);
        float4 c1 = *(const float4*)(worow + 16 + 4 * quad);
        float4 c2 = *(const float4*)(worow + 32 + 4 * quad);
        float4 c3 = *(const float4*)(worow + 48 + 4 * quad);
        frag_u f0, f1;
        f0.u[0] = pack4bf(c0.x, c0.y, c0.z, c0.w);
        f0.u[1] = pack4bf(c1.x, c1.y, c1.z, c1.w);
        f1.u[0] = pack4bf(c2.x, c2.y, c2.z, c2.w);
        f1.u[1] = pack4bf(c3.x, c3.y, c3.z, c3.w);
        wf[et][0] = f0.v;
        wf[et][1] = f1.v;
    }
    float biasr[4];
    #pragma unroll
    for (int et = 0; et < 4; et++) biasr[et] = bo[et * 16 + m];

    #pragma unroll
    for (int g = 0; g < 4; g++) {
        const float inv = 1.f / lsum[g];
        frag_u af0, af1;
        af0.u[0] = pack4bf(o[g][0][0] * inv, o[g][0][1] * inv, o[g][0][2] * inv, o[g][0][3] * inv);
        af0.u[1] = pack4bf(o[g][1][0] * inv, o[g][1][1] * inv, o[g][1][2] * inv, o[g][1][3] * inv);
        af1.u[0] = pack4bf(o[g][2][0] * inv, o[g][2][1] * inv, o[g][2][2] * inv, o[g][2][3] * inv);
        af1.u[1] = pack4bf(o[g][3][0] * inv, o[g][3][1] * inv, o[g][3][2] * inv, o[g][3][3] * inv);
        #pragma unroll
        for (int et = 0; et < 4; et++) {
            f32x4 acc = {0.f, 0.f, 0.f, 0.f};
            acc = MFMA(af0.v, wf[et][0], acc);
            acc = MFMA(af1.v, wf[et][1], acc);
            #pragma unroll
            for (int r = 0; r < 4; r++) {
                size_t row = (size_t)bh * S + q0 + g * 16 + quad * 4 + r;
                out[row * 64 + et * 16 + m] = acc[r] + biasr[et];
            }
        }
    }
}

// ---------------------------------------------------------------------------
extern "C" void kernel_launch(void* const* d_in, const int* in_sizes, int n_in,
                              void* d_out, int out_size, void* d_ws, size_t ws_size,
                              hipStream_t stream) {
    const float* x  = (const float*)d_in[0];
    const float* Wq = (const float*)d_in[1];
    const float* bq = (const float*)d_in[2];
    const float* Wk = (const float*)d_in[3];
    const float* bk = (const float*)d_in[4];
    const float* Wv = (const float*)d_in[5];
    const float* bv = (const float*)d_in[6];
    const float* Wo = (const float*)d_in[7];
    const float* bo = (const float*)d_in[8];
    float* out = (float*)d_out;

    attn<<<dim3(192, 4), 256, 0, stream>>>(x, Wq, bq, Wk, bk, Wv, bv, Wo, bo, out);
}

// Round 4
// 214.627 us; speedup vs baseline: 1.9707x; 1.9707x over previous
//
#include <hip/hip_runtime.h>
#include <math.h>

// B=16, H=12, S=1024, D=64.  BH=192, rows = B*H*S = 196608.
// R4: single fused kernel (no prep, no workspace), spill fixed + deeper pipe.
//   - __launch_bounds__(256,2): R3's (256,4) halved the reg budget to 64 arch
//     VGPRs -> 1.5 GB scratch traffic (FETCH 719MB/WRITE 752MB), 423 us.
//   - K/V LDS tiles double-buffered: ONE barrier per 64-key step; next tile's
//     global x loads + proj MFMAs interleave with current tile's QK/PV.
//   - Wk/Wv staged once into their own LDS (not aliased), before prologue sync.
// LDS = union(xq 36.9K, k/v dbuf 36.9K) + w 18.4K = 55.3 KB -> 2 blocks/CU.
//
// KEY-PERMUTATION TRICK (unchanged): P^T exits QK in C-layout; reinterpreted
// as a B-fragment it supplies key kappa(s) at MFMA k-slot s.  Vt and Wo are
// stored/loaded pre-permuted by kappa so P and O feed MFMA from registers.
// kappa: s = 16t + 4q + r  ->  32*(t>>1) + 8*q + 4*(t&1) + r.

typedef __bf16 bf16x8 __attribute__((ext_vector_type(8)));
typedef float  f32x4  __attribute__((ext_vector_type(4)));

#define MFMA(a, b, c) __builtin_amdgcn_mfma_f32_16x16x32_bf16((a), (b), (c), 0, 0, 0)

static constexpr int S = 1024;
static constexpr int PAD = 72;      // 144 B row stride: 16B-aligned, breaks 128B aliasing
// Q prescale: 1/sqrt(64) * log2(e)  -> scores arrive pre-scaled for exp2
static constexpr float QSCALE = 0.125f * 1.4426950408889634f;

__device__ inline unsigned long long pack4bf(float a, float b, float c, float d) {
    union { __bf16 h[4]; unsigned long long u; } pk;
    pk.h[0] = (__bf16)a; pk.h[1] = (__bf16)b; pk.h[2] = (__bf16)c; pk.h[3] = (__bf16)d;
    return pk.u;
}

union frag_u { bf16x8 v; unsigned long long u[2]; };

// ---------------------------------------------------------------------------
__global__ __launch_bounds__(256, 2) void attn(
    const float* __restrict__ x,
    const float* __restrict__ Wq, const float* __restrict__ bq,
    const float* __restrict__ Wk, const float* __restrict__ bk,
    const float* __restrict__ Wv, const float* __restrict__ bv,
    const float* __restrict__ Wo, const float* __restrict__ bo,
    float* __restrict__ out)
{
    __shared__ __align__(16) union {
        __bf16 xq[256][PAD];            // prologue: x (q rows), then Q roundtrip
        struct {
            __bf16 k[2][64][PAD];       // K tile [key][d], double-buffered
            __bf16 v[2][64][PAD];       // Vt tile [d][key-kappa], double-buffered
        } m;
    } L;
    __shared__ __align__(16) __bf16 lw[2][64][PAD];   // Wk, Wv (persist)

    const int tid = threadIdx.x;
    const int w = tid >> 6, lane = tid & 63, m = lane & 15, quad = lane >> 4;
    const int bh = blockIdx.x;
    const int q0 = blockIdx.y * 256 + w * 64;

    // ---- prologue: stage my 256 x-rows fp32->bf16, and Wk/Wv tiles ----
    const float* xq32 = x + ((size_t)bh * 1024 + blockIdx.y * 256) * 64;
    #pragma unroll
    for (int i = tid * 4; i < 16384; i += 1024) {
        float4 v = *(const float4*)(xq32 + i);
        int r = i >> 6, c = i & 63;
        *(unsigned long long*)&L.xq[r][c] = pack4bf(v.x, v.y, v.z, v.w);
    }
    #pragma unroll
    for (int i = tid * 4; i < 4096; i += 1024) {
        int r = i >> 6, c = i & 63;
        float4 a = *(const float4*)(Wk + i);
        *(unsigned long long*)&lw[0][r][c] = pack4bf(a.x, a.y, a.z, a.w);
        float4 b = *(const float4*)(Wv + i);
        *(unsigned long long*)&lw[1][r][c] = pack4bf(b.x, b.y, b.z, b.w);
    }
    __syncthreads();

    // xqf read, Q-proj write, qf read: all touch only this wave's 64 rows
    // (w*64 .. w*64+63), so no barriers needed until the union is re-purposed.
    bf16x8 xqf[4][2];
    #pragma unroll
    for (int g = 0; g < 4; g++) {
        xqf[g][0] = *(const bf16x8*)&L.xq[w * 64 + g * 16 + m][quad * 8];
        xqf[g][1] = *(const bf16x8*)&L.xq[w * 64 + g * 16 + m][32 + quad * 8];
    }
    #pragma unroll
    for (int et = 0; et < 4; et++) {
        const float* wqrow = Wq + (size_t)(et * 16 + m) * 64;
        float4 a0 = *(const float4*)(wqrow + quad * 8);
        float4 a1 = *(const float4*)(wqrow + quad * 8 + 4);
        float4 a2 = *(const float4*)(wqrow + 32 + quad * 8);
        float4 a3 = *(const float4*)(wqrow + 36 + quad * 8);
        frag_u wf0, wf1;
        wf0.u[0] = pack4bf(a0.x, a0.y, a0.z, a0.w);
        wf0.u[1] = pack4bf(a1.x, a1.y, a1.z, a1.w);
        wf1.u[0] = pack4bf(a2.x, a2.y, a2.z, a2.w);
        wf1.u[1] = pack4bf(a3.x, a3.y, a3.z, a3.w);
        float4 bias = *(const float4*)(bq + et * 16 + quad * 4);
        #pragma unroll
        for (int g = 0; g < 4; g++) {
            f32x4 acc = {0.f, 0.f, 0.f, 0.f};
            acc = MFMA(wf0.v, xqf[g][0], acc);
            acc = MFMA(wf1.v, xqf[g][1], acc);
            *(unsigned long long*)&L.xq[w * 64 + g * 16 + m][et * 16 + quad * 4] =
                pack4bf((acc[0] + bias.x) * QSCALE, (acc[1] + bias.y) * QSCALE,
                        (acc[2] + bias.z) * QSCALE, (acc[3] + bias.w) * QSCALE);
        }
    }
    bf16x8 qf[4][2];
    #pragma unroll
    for (int g = 0; g < 4; g++) {
        qf[g][0] = *(const bf16x8*)&L.xq[w * 64 + g * 16 + m][quad * 8];
        qf[g][1] = *(const bf16x8*)&L.xq[w * 64 + g * 16 + m][32 + quad * 8];
    }
    __syncthreads();    // everyone done with xq; union becomes k/v buffers

    float4 bkr[4];
    float  bvr[4];
    #pragma unroll
    for (int et = 0; et < 4; et++) {
        bkr[et] = *(const float4*)(bk + et * 16 + quad * 4);
        bvr[et] = bv[et * 16 + m];
    }

    f32x4 o[4][4];
    float lsum[4] = {0.f, 0.f, 0.f, 0.f};
    #pragma unroll
    for (int g = 0; g < 4; g++)
        #pragma unroll
        for (int n = 0; n < 4; n++) o[g][n] = {0.f, 0.f, 0.f, 0.f};

    const float* xk32 = x + (size_t)bh * 1024 * 64;          // fp32 keys, this bh
    const int p0 = 32 * (w >> 1) + 8 * quad + 4 * (w & 1);   // kappa base, tile t=w

    // ---- tile 0 projected into buffer 0 ----
    {
        const float* xrow = xk32 + (size_t)(w * 16 + m) * 64;
        float4 a0 = *(const float4*)(xrow + quad * 8);
        float4 a1 = *(const float4*)(xrow + quad * 8 + 4);
        float4 a2 = *(const float4*)(xrow + 32 + quad * 8);
        float4 a3 = *(const float4*)(xrow + 36 + quad * 8);
        frag_u xk0, xk1;
        xk0.u[0] = pack4bf(a0.x, a0.y, a0.z, a0.w);
        xk0.u[1] = pack4bf(a1.x, a1.y, a1.z, a1.w);
        xk1.u[0] = pack4bf(a2.x, a2.y, a2.z, a2.w);
        xk1.u[1] = pack4bf(a3.x, a3.y, a3.z, a3.w);
        #pragma unroll
        for (int et = 0; et < 4; et++) {
            bf16x8 kw0 = *(const bf16x8*)&lw[0][et * 16 + m][quad * 8];
            bf16x8 kw1 = *(const bf16x8*)&lw[0][et * 16 + m][32 + quad * 8];
            f32x4 ka = {0.f, 0.f, 0.f, 0.f};
            ka = MFMA(kw0, xk0.v, ka);
            ka = MFMA(kw1, xk1.v, ka);
            *(unsigned long long*)&L.m.k[0][w * 16 + m][et * 16 + quad * 4] =
                pack4bf(ka[0] + bkr[et].x, ka[1] + bkr[et].y,
                        ka[2] + bkr[et].z, ka[3] + bkr[et].w);
            bf16x8 vw0 = *(const bf16x8*)&lw[1][et * 16 + m][quad * 8];
            bf16x8 vw1 = *(const bf16x8*)&lw[1][et * 16 + m][32 + quad * 8];
            f32x4 va = {0.f, 0.f, 0.f, 0.f};
            va = MFMA(xk0.v, vw0, va);
            va = MFMA(xk1.v, vw1, va);
            *(unsigned long long*)&L.m.v[0][et * 16 + m][p0] =
                pack4bf(va[0] + bvr[et], va[1] + bvr[et],
                        va[2] + bvr[et], va[3] + bvr[et]);
        }
    }

    // ---- main loop: 1 barrier per 64-key step; proj(kb+1) overlaps compute(kb) ----
    for (int kb = 0; kb < 16; kb++) {
        __syncthreads();                 // buf[cur] complete for all waves
        const int cur = kb & 1;

        // issue next tile's x loads early (latency hides under compute)
        float4 a0, a1, a2, a3;
        if (kb < 15) {
            const float* xrow = xk32 + (size_t)((kb + 1) * 64 + w * 16 + m) * 64;
            a0 = *(const float4*)(xrow + quad * 8);
            a1 = *(const float4*)(xrow + quad * 8 + 4);
            a2 = *(const float4*)(xrow + 32 + quad * 8);
            a3 = *(const float4*)(xrow + 36 + quad * 8);
        }

        // ---- compute phase: QK -> exp2 -> PV on buf[cur] ----
        #pragma unroll
        for (int gp = 0; gp < 2; gp++) {
            frag_u pb[2][2];
            #pragma unroll
            for (int t = 0; t < 4; t++) {
                bf16x8 ka0 = *(const bf16x8*)&L.m.k[cur][t * 16 + m][quad * 8];
                bf16x8 ka1 = *(const bf16x8*)&L.m.k[cur][t * 16 + m][32 + quad * 8];
                #pragma unroll
                for (int gl = 0; gl < 2; gl++) {
                    const int g = gp * 2 + gl;
                    f32x4 acc = {0.f, 0.f, 0.f, 0.f};
                    acc = MFMA(ka0, qf[g][0], acc);
                    acc = MFMA(ka1, qf[g][1], acc);
                    float e0 = __builtin_amdgcn_exp2f(acc[0]);
                    float e1 = __builtin_amdgcn_exp2f(acc[1]);
                    float e2 = __builtin_amdgcn_exp2f(acc[2]);
                    float e3 = __builtin_amdgcn_exp2f(acc[3]);
                    lsum[g] += (e0 + e1) + (e2 + e3);
                    pb[gl][t >> 1].u[t & 1] = pack4bf(e0, e1, e2, e3);
                }
            }
            #pragma unroll
            for (int n = 0; n < 4; n++) {
                bf16x8 va0 = *(const bf16x8*)&L.m.v[cur][n * 16 + m][quad * 8];
                bf16x8 va1 = *(const bf16x8*)&L.m.v[cur][n * 16 + m][32 + quad * 8];
                #pragma unroll
                for (int gl = 0; gl < 2; gl++) {
                    const int g = gp * 2 + gl;
                    o[g][n] = MFMA(va0, pb[gl][0].v, o[g][n]);
                    o[g][n] = MFMA(va1, pb[gl][1].v, o[g][n]);
                }
            }
        }

        // ---- proj phase: project tile kb+1 into buf[cur^1] (no barrier) ----
        if (kb < 15) {
            frag_u xk0, xk1;
            xk0.u[0] = pack4bf(a0.x, a0.y, a0.z, a0.w);
            xk0.u[1] = pack4bf(a1.x, a1.y, a1.z, a1.w);
            xk1.u[0] = pack4bf(a2.x, a2.y, a2.z, a2.w);
            xk1.u[1] = pack4bf(a3.x, a3.y, a3.z, a3.w);
            #pragma unroll
            for (int et = 0; et < 4; et++) {
                bf16x8 kw0 = *(const bf16x8*)&lw[0][et * 16 + m][quad * 8];
                bf16x8 kw1 = *(const bf16x8*)&lw[0][et * 16 + m][32 + quad * 8];
                f32x4 ka = {0.f, 0.f, 0.f, 0.f};
                ka = MFMA(kw0, xk0.v, ka);
                ka = MFMA(kw1, xk1.v, ka);
                *(unsigned long long*)&L.m.k[cur ^ 1][w * 16 + m][et * 16 + quad * 4] =
                    pack4bf(ka[0] + bkr[et].x, ka[1] + bkr[et].y,
                            ka[2] + bkr[et].z, ka[3] + bkr[et].w);
                bf16x8 vw0 = *(const bf16x8*)&lw[1][et * 16 + m][quad * 8];
                bf16x8 vw1 = *(const bf16x8*)&lw[1][et * 16 + m][32 + quad * 8];
                f32x4 va = {0.f, 0.f, 0.f, 0.f};
                va = MFMA(xk0.v, vw0, va);
                va = MFMA(xk1.v, vw1, va);
                *(unsigned long long*)&L.m.v[cur ^ 1][et * 16 + m][p0] =
                    pack4bf(va[0] + bvr[et], va[1] + bvr[et],
                            va[2] + bvr[et], va[3] + bvr[et]);
            }
        }
    }

    // ---- epilogue: l reduce, O^T regs -> A-fragments, fused @ Wo + bo ----
    #pragma unroll
    for (int g = 0; g < 4; g++) {
        lsum[g] += __shfl_xor(lsum[g], 16);
        lsum[g] += __shfl_xor(lsum[g], 32);
    }

    // Wo fragments with kappa folded into the load addresses:
    bf16x8 wf[4][2];
    #pragma unroll
    for (int et = 0; et < 4; et++) {
        const float* worow = Wo + (size_t)(et * 16 + m) * 64;
        float4 c0 = *(const float4*)(worow + 4 * quad);
        float4 c1 = *(const float4*)(worow + 16 + 4 * quad);
        float4 c2 = *(const float4*)(worow + 32 + 4 * quad);
        float4 c3 = *(const float4*)(worow + 48 + 4 * quad);
        frag_u f0, f1;
        f0.u[0] = pack4bf(c0.x, c0.y, c0.z, c0.w);
        f0.u[1] = pack4bf(c1.x, c1.y, c1.z, c1.w);
        f1.u[0] = pack4bf(c2.x, c2.y, c2.z, c2.w);
        f1.u[1] = pack4bf(c3.x, c3.y, c3.z, c3.w);
        wf[et][0] = f0.v;
        wf[et][1] = f1.v;
    }
    float biasr[4];
    #pragma unroll
    for (int et = 0; et < 4; et++) biasr[et] = bo[et * 16 + m];

    #pragma unroll
    for (int g = 0; g < 4; g++) {
        const float inv = 1.f / lsum[g];
        frag_u af0, af1;
        af0.u[0] = pack4bf(o[g][0][0] * inv, o[g][0][1] * inv, o[g][0][2] * inv, o[g][0][3] * inv);
        af0.u[1] = pack4bf(o[g][1][0] * inv, o[g][1][1] * inv, o[g][1][2] * inv, o[g][1][3] * inv);
        af1.u[0] = pack4bf(o[g][2][0] * inv, o[g][2][1] * inv, o[g][2][2] * inv, o[g][2][3] * inv);
        af1.u[1] = pack4bf(o[g][3][0] * inv, o[g][3][1] * inv, o[g][3][2] * inv, o[g][3][3] * inv);
        #pragma unroll
        for (int et = 0; et < 4; et++) {
            f32x4 acc = {0.f, 0.f, 0.f, 0.f};
            acc = MFMA(af0.v, wf[et][0], acc);
            acc = MFMA(af1.v, wf[et][1], acc);
            #pragma unroll
            for (int r = 0; r < 4; r++) {
                size_t row = (size_t)bh * S + q0 + g * 16 + quad * 4 + r;
                out[row * 64 + et * 16 + m] = acc[r] + biasr[et];
            }
        }
    }
}

// ---------------------------------------------------------------------------
extern "C" void kernel_launch(void* const* d_in, const int* in_sizes, int n_in,
                              void* d_out, int out_size, void* d_ws, size_t ws_size,
                              hipStream_t stream) {
    const float* x  = (const float*)d_in[0];
    const float* Wq = (const float*)d_in[1];
    const float* bq = (const float*)d_in[2];
    const float* Wk = (const float*)d_in[3];
    const float* bk = (const float*)d_in[4];
    const float* Wv = (const float*)d_in[5];
    const float* bv = (const float*)d_in[6];
    const float* Wo = (const float*)d_in[7];
    const float* bo = (const float*)d_in[8];
    float* out = (float*)d_out;

    attn<<<dim3(192, 4), 256, 0, stream>>>(x, Wq, bq, Wk, bk, Wv, bv, Wo, bo, out);
}